// Round 9
// baseline (300.112 us; speedup 1.0000x reference)
//
#include <hip/hip_runtime.h>

#define BATCH 16384
#define RT    32        // batch rows per block -> 512 blocks -> 2 blocks/CU

typedef unsigned short u16;
typedef __attribute__((ext_vector_type(8))) short short8;
typedef __attribute__((ext_vector_type(8))) _Float16 f16x8;
typedef __attribute__((ext_vector_type(4))) float f32x4;

// ---------- fp16 helpers (storage = u16 bit patterns) ----------
__device__ __forceinline__ u16 f2h(float x) {
    union { _Float16 h; u16 u; } c; c.h = (_Float16)x; return c.u;
}
__device__ __forceinline__ float h2f(u16 b) {
    union { u16 u; _Float16 h; } c; c.u = b; return (float)c.h;
}
__device__ __forceinline__ unsigned int pk2(float a, float b) {
    union { __attribute__((ext_vector_type(2))) __fp16 v; unsigned int u; } c;
    c.v = __builtin_amdgcn_cvt_pkrtz(a, b);
    return c.u;
}
// 16-lane sum via DPP (pure VALU, no DS pipe): quad xor1, xor2, row_ror 4, 8
__device__ __forceinline__ float red16(float x) {
    x += __builtin_bit_cast(float, __builtin_amdgcn_update_dpp(
             0, __builtin_bit_cast(int, x), 0xB1, 0xF, 0xF, true));
    x += __builtin_bit_cast(float, __builtin_amdgcn_update_dpp(
             0, __builtin_bit_cast(int, x), 0x4E, 0xF, 0xF, true));
    x += __builtin_bit_cast(float, __builtin_amdgcn_update_dpp(
             0, __builtin_bit_cast(int, x), 0x124, 0xF, 0xF, true));
    x += __builtin_bit_cast(float, __builtin_amdgcn_update_dpp(
             0, __builtin_bit_cast(int, x), 0x128, 0xF, 0xF, true));
    return x;
}

// ================= weight pre-pack kernels (single fp16) =================
__global__ void prep_w1(const float* __restrict__ W1, const int* __restrict__ G,
                        u16* __restrict__ P) {
    int idx = blockIdx.x * 256 + threadIdx.x;   // 64*64*256 exactly
    int n = idx & 255;
    int k = (idx >> 8) & 63;
    int v = idx >> 14;
    float w = (G[k * 64 + v] > 0) ? W1[((size_t)v * 65 + k) * 256 + n] : 0.0f;
    P[(((size_t)(v * 8 + (k >> 3)) * 256 + n) << 3) + (k & 7)] = f2h(w);
}
__global__ void prep_w2(const float* __restrict__ W2, u16* __restrict__ P) {
    int idx = blockIdx.x * 256 + threadIdx.x;   // 64*256*128 exactly
    int n = idx & 127;
    int k = (idx >> 7) & 255;
    int v = idx >> 15;
    P[(((size_t)(v * 32 + (k >> 3)) * 128 + n) << 3) + (k & 7)] =
        f2h(W2[((size_t)v * 256 + k) * 128 + n]);
}

// ================= persistent fused kernel =================
#define AST   72     // Y-tile stride (u16): 144B = 16 mod 128
#define H1ST  264    // h1 stride (u16): 528B = 16 mod 128

struct StepRegs {               // prefetched one step ahead
    f16x8 p1[2][2];             // W1 fragments [kt][ni]
    float u0, u1;               // u for rows lr / 16+lr
    float b2c, w3c;             // per-col layer-2 bias / layer-3 weight
};

__device__ __forceinline__ void load_step(StepRegs& S, int v,
        const float* __restrict__ U, const u16* __restrict__ P1,
        const float* __restrict__ b2, const float* __restrict__ W3,
        int row0, int mg, int cg, int lr, int lk)
{
    #pragma unroll
    for (int kt = 0; kt < 2; ++kt)
        #pragma unroll
        for (int ni = 0; ni < 2; ++ni)
            S.p1[kt][ni] = *(const f16x8*)&P1[
                (((size_t)(v * 8 + kt * 4 + lk) * 256) + mg * 32 + ni * 16 + lr) << 3];
    S.u0  = U[(size_t)(row0 + lr) * 64 + v];
    S.u1  = U[(size_t)(row0 + 16 + lr) * 64 + v];
    S.b2c = b2[v * 128 + cg * 16 + lr];
    S.w3c = W3[v * 128 + cg * 16 + lr];
}

__device__ __forceinline__ void sen_step(int v, StepRegs& cur, StepRegs& nxt,
        const float* __restrict__ U, const u16* __restrict__ P1,
        const u16* __restrict__ P2, const float* __restrict__ W1,
        const float* __restrict__ b1, const float* __restrict__ b2,
        const float* __restrict__ W3, const float* __restrict__ b3,
        u16* Ah, u16* Al, u16* h1, float (*yp)[RT],
        int row0, int mg, int cg, int lr, int lk, int tid)
{
    // ---- issue this step's P2 fragments (consumed in phase 2, ~phase-1 slack)
    f16x8 p2[8];
    #pragma unroll
    for (int kt = 0; kt < 8; ++kt)
        p2[kt] = *(const f16x8*)&P2[
            (((size_t)(v * 32 + kt * 4 + lk) * 128) + cg * 16 + lr) << 3];
    // ---- issue fp32 params used in phase-1 epilogue (~MFMA-loop slack)
    f32x4 b1v[2], w64v[2];
    #pragma unroll
    for (int ni = 0; ni < 2; ++ni) {
        const int dim = mg * 32 + ni * 16 + lk * 4;
        b1v[ni]  = *(const f32x4*)(b1 + v * 256 + dim);
        w64v[ni] = *(const f32x4*)(W1 + ((size_t)v * 65 + 64) * 256 + dim);
    }

    // ======== Phase 1 — Layer 1 (operand-swapped): h1t[dim][brow] ========
    f32x4 acc1[2][2];
    #pragma unroll
    for (int nj = 0; nj < 2; ++nj)
        #pragma unroll
        for (int ni = 0; ni < 2; ++ni) acc1[nj][ni] = (f32x4){0.f, 0.f, 0.f, 0.f};

    #pragma unroll
    for (int kt = 0; kt < 2; ++kt) {
        f16x8 Yfh[2], Yfl[2];
        #pragma unroll
        for (int nj = 0; nj < 2; ++nj) {
            const int o = (nj * 16 + lr) * AST + kt * 32 + lk * 8;
            Yfh[nj] = *(const f16x8*)&Ah[o];
            Yfl[nj] = *(const f16x8*)&Al[o];
        }
        #pragma unroll
        for (int ni = 0; ni < 2; ++ni)
            #pragma unroll
            for (int nj = 0; nj < 2; ++nj) {
                acc1[nj][ni] = __builtin_amdgcn_mfma_f32_16x16x32_f16(cur.p1[kt][ni], Yfh[nj], acc1[nj][ni], 0, 0, 0);
                acc1[nj][ni] = __builtin_amdgcn_mfma_f32_16x16x32_f16(cur.p1[kt][ni], Yfl[nj], acc1[nj][ni], 0, 0, 0);
            }
    }

    // ---- prefetch NEXT step's P1 fragments + scalars (full-step slack) ----
    {
        int vn = v + 1; if (vn > 63) vn = 63;
        load_step(nxt, vn, U, P1, b2, W3, row0, mg, cg, lr, lk);
    }

    // ---- epilogue: + bias + u * W1[64,:], relu, fp16 pack (RTZ), store ----
    const float uu[2] = {cur.u0, cur.u1};
    #pragma unroll
    for (int nj = 0; nj < 2; ++nj) {
        const int brow = nj * 16 + lr;
        #pragma unroll
        for (int ni = 0; ni < 2; ++ni) {
            float x[4];
            #pragma unroll
            for (int r = 0; r < 4; ++r)
                x[r] = fmaxf(acc1[nj][ni][r] + b1v[ni][r] + uu[nj] * w64v[ni][r], 0.0f);
            unsigned long long pk = (unsigned long long)pk2(x[0], x[1])
                                  | ((unsigned long long)pk2(x[2], x[3]) << 32);
            *(unsigned long long*)&h1[brow * H1ST + mg * 32 + ni * 16 + lk * 4] = pk;
        }
    }
    __syncthreads();   // B1: h1 written -> phase 2 may read

    // ======== Phase 2 — Layer 2 (bias via acc init) + in-reg layer 3 ========
    f32x4 acc2[2];
    acc2[0] = (f32x4){cur.b2c, cur.b2c, cur.b2c, cur.b2c};
    acc2[1] = acc2[0];
    #pragma unroll
    for (int kt = 0; kt < 8; ++kt) {
        f16x8 Hf[2];
        #pragma unroll
        for (int mi = 0; mi < 2; ++mi)
            Hf[mi] = *(const f16x8*)&h1[(mi * 16 + lr) * H1ST + kt * 32 + lk * 8];
        #pragma unroll
        for (int mi = 0; mi < 2; ++mi)
            acc2[mi] = __builtin_amdgcn_mfma_f32_16x16x32_f16(Hf[mi], p2[kt], acc2[mi], 0, 0, 0);
    }
    // layer-3 partials: relu * w3, DPP-reduce over the 16 lr lanes
    f32x4 sv[2];
    #pragma unroll
    for (int mi = 0; mi < 2; ++mi)
        #pragma unroll
        for (int r = 0; r < 4; ++r)
            sv[mi][r] = red16(fmaxf(acc2[mi][r], 0.0f) * cur.w3c);
    if (lr == 0) {
        *(f32x4*)&yp[cg][lk * 4]      = sv[0];
        *(f32x4*)&yp[cg][16 + lk * 4] = sv[1];
    }
    __syncthreads();   // B2: yp visible; all h1 reads done

    // ======== Phase 3 — finalize y column into the Y tile ========
    if (tid < RT) {
        float y = b3[v];
        #pragma unroll
        for (int c = 0; c < 8; ++c) y += yp[c][tid];
        u16 h = f2h(y);
        Ah[tid * AST + v] = h;
        Al[tid * AST + v] = f2h(y - h2f(h));
    }
    __syncthreads();   // B3: Y col v visible; h1 free for next step
}

__global__ __launch_bounds__(512, 4)
void sen_fused(const float* __restrict__ U,
               const u16* __restrict__ P1, const u16* __restrict__ P2,
               const float* __restrict__ W1, const float* __restrict__ b1,
               const float* __restrict__ b2, const float* __restrict__ W3,
               const float* __restrict__ b3, float* __restrict__ Y)
{
    __shared__ __attribute__((aligned(16))) u16 Ah[RT * AST];
    __shared__ __attribute__((aligned(16))) u16 Al[RT * AST];
    __shared__ __attribute__((aligned(16))) u16 h1[RT * H1ST];
    __shared__ float yp[8][RT];

    const int tid  = threadIdx.x;
    const int row0 = blockIdx.x * RT;

    // zero Y tile incl. pad (stale LDS bits could be NaN; NaN*0 = NaN in MFMA)
    {
        short8 z = {0,0,0,0,0,0,0,0};
        for (int i = tid; i < (RT * AST) / 8; i += 512) {
            *(short8*)&Ah[i * 8] = z;
            *(short8*)&Al[i * 8] = z;
        }
    }
    __syncthreads();

    const int w  = tid >> 6, l = tid & 63;
    const int lr = l & 15,  lk = l >> 4;
    const int mg = w;   // phase 1: dim group (32 dims, W1 read once/block)
    const int cg = w;   // phase 2: col group (16 cols, W2 read once/block)

    StepRegs A, B;
    load_step(A, 0, U, P1, b2, W3, row0, mg, cg, lr, lk);

    #pragma unroll 1
    for (int vh = 0; vh < 32; ++vh) {
        sen_step(2 * vh,     A, B, U, P1, P2, W1, b1, b2, W3, b3,
                 Ah, Al, h1, yp, row0, mg, cg, lr, lk, tid);
        sen_step(2 * vh + 1, B, A, U, P1, P2, W1, b1, b2, W3, b3,
                 Ah, Al, h1, yp, row0, mg, cg, lr, lk, tid);
    }

    // ---- final coalesced store (hi+lo reconstruct), 1 float4 per thread ----
    {
        const int row = tid >> 4, c4 = (tid & 15) * 4;
        const u16* hv = &Ah[row * AST + c4];
        const u16* lv = &Al[row * AST + c4];
        float4 o;
        o.x = h2f(hv[0]) + h2f(lv[0]);
        o.y = h2f(hv[1]) + h2f(lv[1]);
        o.z = h2f(hv[2]) + h2f(lv[2]);
        o.w = h2f(hv[3]) + h2f(lv[3]);
        *(float4*)(Y + (size_t)(row0 + row) * 64 + c4) = o;
    }
}

extern "C" void kernel_launch(void* const* d_in, const int* in_sizes, int n_in,
                              void* d_out, int out_size, void* d_ws, size_t ws_size,
                              hipStream_t stream) {
    // inputs: X, U, causal_graph, W1, b1, W2, b2, W3, b3  (X never feeds the recursion)
    const float* U  = (const float*)d_in[1];
    const int*   G  = (const int*)  d_in[2];
    const float* W1 = (const float*)d_in[3];
    const float* b1 = (const float*)d_in[4];
    const float* W2 = (const float*)d_in[5];
    const float* b2 = (const float*)d_in[6];
    const float* W3 = (const float*)d_in[7];
    const float* b3 = (const float*)d_in[8];
    float* Y = (float*)d_out;

    const size_t S1 = (size_t)64 * 64 * 256;     // u16 elements, packed W1
    u16* P1 = (u16*)d_ws;
    u16* P2 = P1 + S1;

    prep_w1<<<(64 * 64 * 256) / 256, 256, 0, stream>>>(W1, G, P1);
    prep_w2<<<(64 * 256 * 128) / 256, 256, 0, stream>>>(W2, P2);
    sen_fused<<<BATCH / RT, 512, 0, stream>>>(U, P1, P2, W1, b1, b2, W3, b3, Y);
}